// Round 10
// baseline (705.295 us; speedup 1.0000x reference)
//
#include <hip/hip_runtime.h>
#include <stdint.h>

typedef __bf16 bf16;
typedef bf16 bf16x8 __attribute__((ext_vector_type(8)));
typedef float f32x4 __attribute__((ext_vector_type(4)));

#define B_ROWS   65536
#define K1       784
#define N1       256
#define FLAG_CAP 262144

// workspace layout (bytes)
#define CNT_OFF  0          // 4 B flag counter
#define LIST_OFF 4096       // 1 MB flag list
#define S1P_OFF  1052672    // 256x800 bf16 sign(w1), zero-padded K -> 409600 B
#define W2P_OFF  1462272    // 128x8 u32 packed sign(w2) -> 4096 B
#define W3P_OFF  1466368    // 32x4 u32 packed sign(w3) -> 512 B
#define W4P_OFF  1466880    // 16 u32 packed sign(w4) -> 64 B
#define H1P_OFF  1470464    // 65536x8 u32 packed h1 signs -> 2 MB

// ---------------- prep: binarize/pack weights, zero flag counter ----------------
__global__ __launch_bounds__(256) void prep_kernel(
    const float* __restrict__ w1, const float* __restrict__ w2,
    const float* __restrict__ w3, const float* __restrict__ w4,
    bf16* __restrict__ s1p, uint32_t* __restrict__ w2p,
    uint32_t* __restrict__ w3p, uint32_t* __restrict__ w4p,
    uint32_t* __restrict__ cnt) {
  int gid = blockIdx.x * 256 + threadIdx.x;
  if (gid == 0) *cnt = 0u;
  if (gid < 256 * 800) {
    int n = gid / 800, k = gid - n * 800;
    bf16 v = (bf16)0.0f;
    if (k < K1) v = (w1[n * K1 + k] >= 0.0f) ? (bf16)1.0f : (bf16)-1.0f;
    s1p[gid] = v;
  }
  if (gid < 1024) {                       // w2: 128 rows x 8 words
    int j = gid >> 3, w = gid & 7;
    uint32_t bits = 0;
    for (int i = 0; i < 32; ++i)
      bits |= (w2[j * 256 + w * 32 + i] >= 0.0f ? 1u : 0u) << i;
    w2p[gid] = bits;
  }
  if (gid < 128) {                        // w3: 32 rows x 4 words
    int j = gid >> 2, w = gid & 3;
    uint32_t bits = 0;
    for (int i = 0; i < 32; ++i)
      bits |= (w3[j * 128 + w * 32 + i] >= 0.0f ? 1u : 0u) << i;
    w3p[gid] = bits;
  }
  if (gid < 16) {                         // w4: 10 rows x 1 word (pad to 16)
    uint32_t bits = 0;
    if (gid < 10)
      for (int i = 0; i < 32; ++i)
        bits |= (w4[gid * 32 + i] >= 0.0f ? 1u : 0u) << i;
    w4p[gid] = bits;
  }
}

// ---------------- layer 1: x @ sign(w1)^T, barrier-free direct-from-global MFMA ----
// Each wave owns a 32-row x 128-col C strip. A and B fragments are loaded
// straight from global (16 B/lane; wave-wide the pattern covers full cache
// lines), hi/lo bf16 split done in registers. NO LDS, NO barriers: 3 waves/SIMD
// of pure TLP hide memory latency. 1024 blocks x 4 waves.
__global__ __launch_bounds__(256, 3) void gemm1_kernel(
    const float* __restrict__ x, const uint8_t* __restrict__ s1b,
    uint8_t* __restrict__ h1b, uint32_t* __restrict__ cnt,
    uint32_t* __restrict__ list) {
  const int tid  = threadIdx.x;
  const int lane = tid & 63;
  const int w    = tid >> 6;
  const int gw   = blockIdx.x * 4 + w;     // 0..4095
  const int strip = gw >> 1;               // rows strip*32 .. +32
  const int n0    = (gw & 1) << 7;         // col half: 0 or 128
  const int fr = lane & 15, fg = lane >> 4;

  f32x4 acc[2][8];
#pragma unroll
  for (int i = 0; i < 2; ++i)
#pragma unroll
    for (int j = 0; j < 8; ++j) acc[i][j] = (f32x4){0.f, 0.f, 0.f, 0.f};

  // A: lane needs x[row = base + fr][k0 + fg*8 .. +8]  (16x16x32 A-layout)
  const float* pA = x + ((size_t)strip * 32 + fr) * K1 + fg * 8;
  // B: lane needs s1p[n = n0 + j*16 + fr][k0 + fg*8 .. +8]
  const uint8_t* pB = s1b + (size_t)(n0 + fr) * 1600 + fg * 16;

  for (int step = 0; step < 25; ++step) {
    const int k0 = step * 32;
    const bool kv = (k0 + fg * 8) < K1;     // zero-fill K pad (step 24, fg>=2)
    float4 z = make_float4(0.f, 0.f, 0.f, 0.f);
    float4 a0 = kv ? *(const float4*)(pA + k0)            : z;
    float4 a1 = kv ? *(const float4*)(pA + k0 + 4)        : z;
    float4 a2 = kv ? *(const float4*)(pA + 16 * K1 + k0)  : z;
    float4 a3 = kv ? *(const float4*)(pA + 16 * K1 + k0 + 4) : z;
    bf16x8 bfr[8];
#pragma unroll
    for (int j = 0; j < 8; ++j)
      bfr[j] = *(const bf16x8*)(pB + (size_t)j * 16 * 1600 + k0 * 2);

    bf16x8 ah[2], al[2];
    {
      float f0[8] = {a0.x, a0.y, a0.z, a0.w, a1.x, a1.y, a1.z, a1.w};
      float f1[8] = {a2.x, a2.y, a2.z, a2.w, a3.x, a3.y, a3.z, a3.w};
#pragma unroll
      for (int q = 0; q < 8; ++q) {
        bf16 h0 = (bf16)f0[q]; ah[0][q] = h0; al[0][q] = (bf16)(f0[q] - (float)h0);
        bf16 h1 = (bf16)f1[q]; ah[1][q] = h1; al[1][q] = (bf16)(f1[q] - (float)h1);
      }
    }
#pragma unroll
    for (int i = 0; i < 2; ++i)
#pragma unroll
      for (int j = 0; j < 8; ++j) {
        acc[i][j] = __builtin_amdgcn_mfma_f32_16x16x32_bf16(ah[i], bfr[j], acc[i][j], 0, 0, 0);
        acc[i][j] = __builtin_amdgcn_mfma_f32_16x16x32_bf16(al[i], bfr[j], acc[i][j], 0, 0, 0);
      }
  }

  // epilogue: ballot-pack signs; wave-aggregated flag atomics (one add/group).
  // C/D layout (verified): col = lane&15 (n), row = (lane>>4)*4 + reg (m).
  const int m0 = strip * 32;
#pragma unroll
  for (int i = 0; i < 2; ++i) {
#pragma unroll
    for (int r = 0; r < 4; ++r) {
      unsigned long long sb[8];
#pragma unroll
      for (int j = 0; j < 8; ++j) {
        float v = acc[i][j][r];
        sb[j] = __ballot(v >= 0.0f);
        bool fl = __builtin_fabsf(v) < 0.05f;
        unsigned long long fm = __ballot(fl);
        if (fm) {
          int leader = __ffsll(fm) - 1;
          uint32_t base = 0;
          if (lane == leader) base = atomicAdd(cnt, (uint32_t)__popcll(fm));
          base = __shfl(base, leader);
          if (fl) {
            uint32_t rank = (uint32_t)__popcll(fm & ((lane == 63) ? ~0ull >> 1
                                                   : ((1ull << lane) - 1)));
            uint32_t pos = base + rank;
            if (pos < FLAG_CAP)
              list[pos] = ((uint32_t)(m0 + i * 16 + fg * 4 + r) << 8) |
                          (uint32_t)(n0 + j * 16 + fr);
          }
        }
      }
      if (fr == 0) {  // lanes 0,16,32,48 write one row's 128 bits (this half)
        int m = m0 + i * 16 + fg * 4 + r;
        int sh = fg * 16;
        uint32_t u0 = (uint32_t)((sb[0] >> sh) & 0xFFFF) | ((uint32_t)((sb[1] >> sh) & 0xFFFF) << 16);
        uint32_t u1 = (uint32_t)((sb[2] >> sh) & 0xFFFF) | ((uint32_t)((sb[3] >> sh) & 0xFFFF) << 16);
        uint32_t u2 = (uint32_t)((sb[4] >> sh) & 0xFFFF) | ((uint32_t)((sb[5] >> sh) & 0xFFFF) << 16);
        uint32_t u3 = (uint32_t)((sb[6] >> sh) & 0xFFFF) | ((uint32_t)((sb[7] >> sh) & 0xFFFF) << 16);
        *(uint4*)(h1b + (size_t)m * 32 + (n0 >> 3)) = make_uint4(u0, u1, u2, u3);
      }
    }
  }
}

// ---------------- cleanup: recompute flagged dots EXACTLY as the fp32 reference ----------------
// VERIFIED (absmax=0): reference = BLIS/AOCL-style sgemm, KC=512, full panels
// then remainder; one fp32 accumulator per C element, ascending k in panel;
// C = fl( seq[0,512) + seq[512,784) ). float4 loads, scalar sequential adds
// (x,y,z,w ascending k) => bit-exact order.
__global__ __launch_bounds__(256) void cleanup_kernel(
    const float* __restrict__ x, const float* __restrict__ w1,
    uint32_t* __restrict__ h1p, const uint32_t* __restrict__ cnt,
    const uint32_t* __restrict__ list) {
  uint32_t n = *cnt;
  if (n > FLAG_CAP) n = FLAG_CAP;
  for (uint32_t idx = blockIdx.x * 256 + threadIdx.x; idx < n; idx += 65536) {
    uint32_t e = list[idx];
    uint32_t col = e & 255u, b = e >> 8;
    const float4* xr4 = (const float4*)(x + (size_t)b * K1);
    const float4* wr4 = (const float4*)(w1 + (size_t)col * K1);
    float t1 = 0.0f, t2 = 0.0f;
    for (int k4 = 0; k4 < 128; ++k4) {          // k in [0,512)
      float4 xv = xr4[k4], wv = wr4[k4];
      t1 += (wv.x >= 0.f) ? xv.x : -xv.x;
      t1 += (wv.y >= 0.f) ? xv.y : -xv.y;
      t1 += (wv.z >= 0.f) ? xv.z : -xv.z;
      t1 += (wv.w >= 0.f) ? xv.w : -xv.w;
    }
    for (int k4 = 128; k4 < 196; ++k4) {        // k in [512,784)
      float4 xv = xr4[k4], wv = wr4[k4];
      t2 += (wv.x >= 0.f) ? xv.x : -xv.x;
      t2 += (wv.y >= 0.f) ? xv.y : -xv.y;
      t2 += (wv.z >= 0.f) ? xv.z : -xv.z;
      t2 += (wv.w >= 0.f) ? xv.w : -xv.w;
    }
    float s = t1 + t2;   // single K-panel join at 512 (BLIS KC)
    uint32_t word = b * 8u + (col >> 5);
    uint32_t mask = 1u << (col & 31u);
    if (s >= 0.0f) atomicOr(&h1p[word], mask);
    else           atomicAnd(&h1p[word], ~mask);
  }
}

// ---------------- layers 2-4: xor/popcount, one thread per batch row ----------------
__global__ __launch_bounds__(256) void layer234_kernel(
    const uint32_t* __restrict__ h1p, const uint32_t* __restrict__ w2p,
    const uint32_t* __restrict__ w3p, const uint32_t* __restrict__ w4p,
    float* __restrict__ out) {
  __shared__ uint32_t lw[1168];  // [0,1024) w2p, [1024,1152) w3p, [1152,1168) w4p
  for (int i = threadIdx.x; i < 1168; i += 256) {
    uint32_t v;
    if (i < 1024) v = w2p[i];
    else if (i < 1152) v = w3p[i - 1024];
    else v = w4p[i - 1152];
    lw[i] = v;
  }
  __syncthreads();
  int b = blockIdx.x * 256 + threadIdx.x;
  const uint4* hp = (const uint4*)h1p;
  uint4 a0 = hp[(size_t)b * 2], a1 = hp[(size_t)b * 2 + 1];
  uint32_t a[8] = {a0.x, a0.y, a0.z, a0.w, a1.x, a1.y, a1.z, a1.w};

  uint32_t h2w[4] = {0u, 0u, 0u, 0u};
#pragma unroll 4
  for (int j = 0; j < 128; ++j) {
    const uint32_t* wr = &lw[j * 8];
    int t = __popc(a[0] ^ wr[0]) + __popc(a[1] ^ wr[1]) +
            __popc(a[2] ^ wr[2]) + __popc(a[3] ^ wr[3]) +
            __popc(a[4] ^ wr[4]) + __popc(a[5] ^ wr[5]) +
            __popc(a[6] ^ wr[6]) + __popc(a[7] ^ wr[7]);
    h2w[j >> 5] |= (uint32_t)(t <= 128) << (j & 31);   // dot = 256-2t >= 0
  }
  uint32_t h3 = 0u;
#pragma unroll 4
  for (int j = 0; j < 32; ++j) {
    const uint32_t* wr = &lw[1024 + j * 4];
    int t = __popc(h2w[0] ^ wr[0]) + __popc(h2w[1] ^ wr[1]) +
            __popc(h2w[2] ^ wr[2]) + __popc(h2w[3] ^ wr[3]);
    h3 |= (uint32_t)(t <= 64) << j;                    // dot = 128-2t >= 0
  }
  float* o = out + (size_t)b * 10;
#pragma unroll
  for (int c = 0; c < 10; ++c) {
    int t = __popc(h3 ^ lw[1152 + c]);
    o[c] = (float)(32 - 2 * t);                        // final logits, no step
  }
}

extern "C" void kernel_launch(void* const* d_in, const int* in_sizes, int n_in,
                              void* d_out, int out_size, void* d_ws, size_t ws_size,
                              hipStream_t stream) {
  const float* x  = (const float*)d_in[0];
  const float* w1 = (const float*)d_in[1];
  const float* w2 = (const float*)d_in[2];
  const float* w3 = (const float*)d_in[3];
  const float* w4 = (const float*)d_in[4];
  float* out = (float*)d_out;
  uint8_t* ws = (uint8_t*)d_ws;

  uint32_t* cnt  = (uint32_t*)(ws + CNT_OFF);
  uint32_t* list = (uint32_t*)(ws + LIST_OFF);
  bf16*     s1p  = (bf16*)(ws + S1P_OFF);
  uint32_t* w2p  = (uint32_t*)(ws + W2P_OFF);
  uint32_t* w3p  = (uint32_t*)(ws + W3P_OFF);
  uint32_t* w4p  = (uint32_t*)(ws + W4P_OFF);
  uint32_t* h1p  = (uint32_t*)(ws + H1P_OFF);

  prep_kernel<<<800, 256, 0, stream>>>(w1, w2, w3, w4, s1p, w2p, w3p, w4p, cnt);
  gemm1_kernel<<<1024, 256, 0, stream>>>(x, (const uint8_t*)s1p,
                                         (uint8_t*)h1p, cnt, list);
  cleanup_kernel<<<256, 256, 0, stream>>>(x, w1, h1p, cnt, list);
  layer234_kernel<<<B_ROWS / 256, 256, 0, stream>>>(h1p, w2p, w3p, w4p, out);
}